// Round 2
// baseline (536.455 us; speedup 1.0000x reference)
//
#include <hip/hip_runtime.h>
#include <hip/hip_bf16.h>
#include <math.h>

#define N_NODES 20000
#define N_EDGES 320000
#define DIN 50
#define HID 1024
#define NC3 726   // 6*121
#define NCLS 121
#define KCAT 2048
#define NQ 242    // [W3bar | S3bar] projected width

typedef __attribute__((ext_vector_type(8))) _Float16 half8;
typedef __attribute__((ext_vector_type(4))) float floatx4;

__device__ __forceinline__ unsigned short f2h(float v) {
    _Float16 h = (_Float16)v;
    return __builtin_bit_cast(unsigned short, h);
}
__device__ __forceinline__ float h2f(unsigned short u) {
    return (float)__builtin_bit_cast(_Float16, u);
}

// async global->LDS, 16B per lane. LDS dest must equal wave-uniform base + lane*16.
__device__ __forceinline__ void async16(const void* g, void* l) {
    __builtin_amdgcn_global_load_lds(
        (const __attribute__((address_space(1))) void*)g,
        (__attribute__((address_space(3))) void*)l,
        16, 0, 0);
}

// ---------------- CSR build ----------------

__global__ void zero_int_kernel(int* p, int n) {
    int i = blockIdx.x * blockDim.x + threadIdx.x;
    if (i < n) p[i] = 0;
}

// exclusive scan of deg -> offs/cursor; also emits dis = deg^-1/2
__global__ __launch_bounds__(1024) void scan_kernel(const int* __restrict__ deg,
                                                    int* __restrict__ offs,
                                                    int* __restrict__ cursor,
                                                    float* __restrict__ dis,
                                                    int n, int total) {
    __shared__ int part[1024];
    int t = threadIdx.x;
    const int CH = (n + 1023) / 1024;
    int base0 = t * CH;
    int s = 0;
    for (int i = 0; i < CH; ++i) {
        int idx = base0 + i;
        if (idx < n) s += deg[idx];
    }
    part[t] = s;
    __syncthreads();
    for (int d = 1; d < 1024; d <<= 1) {
        int v = (t >= d) ? part[t - d] : 0;
        __syncthreads();
        part[t] += v;
        __syncthreads();
    }
    int run = part[t] - s;
    for (int i = 0; i < CH; ++i) {
        int idx = base0 + i;
        if (idx < n) {
            int d = deg[idx];
            offs[idx] = run;
            cursor[idx] = run;
            dis[idx] = d > 0 ? rsqrtf((float)d) : 0.0f;
            run += d;
        }
    }
    if (t == 1023) offs[n] = total;
}

// scatter with inline norm = dis[row]*dis[col]
__global__ void scatter_kernel(const int* __restrict__ row, const int* __restrict__ col,
                               const float* __restrict__ dis, int* __restrict__ cursor,
                               int* __restrict__ csr_src, float* __restrict__ csr_w, int e) {
    int i = blockIdx.x * blockDim.x + threadIdx.x;
    if (i < e) {
        int r = row[i], c = col[i];
        float nm = dis[r] * dis[c];
        int pos = atomicAdd(&cursor[c], 1);
        csr_src[pos] = r;
        csr_w[pos] = nm;
    }
}

// ---------------- merged prep: count_deg + w1t + wt2 transpose + wt3 fold+transpose ----
// blockIdx ranges:  [0,2048) wt2 | [2048,2304) wt3 | [2304,2560) w1t | [2560,3810) count_deg
__global__ __launch_bounds__(256) void prep_kernel(const int* __restrict__ ecol,
                                                   int* __restrict__ deg,
                                                   const float* __restrict__ W1,
                                                   unsigned short* __restrict__ Bt1,
                                                   const float* __restrict__ W2,
                                                   const float* __restrict__ S2,
                                                   unsigned short* __restrict__ Bt2,
                                                   const float* __restrict__ W3,
                                                   const float* __restrict__ S3,
                                                   unsigned short* __restrict__ Bt3) {
    __shared__ unsigned short tile[32][33];
    const int b = blockIdx.x;
    const int tid = threadIdx.x;

    if (b < 2048) {
        // W2/S2 [1024][1024] -> Bt2 fp16 [1024][2048] transposed via LDS 32x32 tiles
        int src = b >> 10;
        int t = b & 1023;
        int k0 = (t >> 5) * 32;
        int n0 = (t & 31) * 32;
        const float* W = src ? S2 : W2;
        int koff = src ? HID : 0;
        int tx = tid & 31;
        int ty = tid >> 5;
#pragma unroll
        for (int r = 0; r < 32; r += 8)
            tile[ty + r][tx] = f2h(W[(size_t)(k0 + ty + r) * HID + n0 + tx]);
        __syncthreads();
#pragma unroll
        for (int r = 0; r < 32; r += 8)
            Bt2[(size_t)(n0 + ty + r) * KCAT + koff + k0 + tx] = tile[tx][ty + r];
    } else if (b < 2304) {
        // W3/S3 [1024][726] -> head-mean + transpose -> Bt3 fp16 [242][1024]
        int tb = b - 2048;
        int src = tb >> 7;
        int t = tb & 127;
        int k0 = (t >> 2) * 32;
        int c0 = (t & 3) * 32;
        const float* W = src ? S3 : W3;
        int tx = tid & 31;
        int ty = tid >> 5;
#pragma unroll
        for (int r = 0; r < 32; r += 8) {
            int k = k0 + ty + r, c = c0 + tx;
            float v = 0.0f;
            if (c < NCLS) {
                const float* p = W + (size_t)k * NC3 + c;
                v = (p[0] + p[121] + p[242] + p[363] + p[484] + p[605]) * (1.0f / 6.0f);
            }
            tile[ty + r][tx] = f2h(v);
        }
        __syncthreads();
#pragma unroll
        for (int r = 0; r < 32; r += 8) {
            int c = c0 + ty + r;
            if (c < NCLS)
                Bt3[(size_t)(src * NCLS + c) * HID + k0 + tx] = tile[tx][ty + r];
        }
    } else if (b < 2560) {
        // W1 [50][1024] -> Bt1 fp16 [1024][64] transposed, padded
        int i = (b - 2304) * 256 + tid;
        int n = i / 64, k = i - n * 64;
        Bt1[i] = (k < DIN) ? f2h(W1[(size_t)k * HID + n]) : (unsigned short)0;
    } else {
        // degree count
        int i = (b - 2560) * 256 + tid;
        if (i < N_EDGES) atomicAdd(&deg[ecol[i]], 1);
    }
}

// ---------------- aggregations ----------------

// gX = A . X  (50-wide fp32 gather -> fp16 out, rows padded to 64)
__global__ __launch_bounds__(64) void aggX_kernel(const float* __restrict__ X,
                                                  const int* __restrict__ offs,
                                                  const int* __restrict__ csr_src,
                                                  const float* __restrict__ csr_w,
                                                  unsigned short* __restrict__ gX) {
    int n = blockIdx.x;
    int t = threadIdx.x;
    float a = 0.0f;
    if (t < DIN) {
        int p0 = offs[n], p1 = offs[n + 1];
        for (int p = p0; p < p1; ++p) {
            a = fmaf(csr_w[p], X[(size_t)csr_src[p] * DIN + t], a);
        }
    }
    gX[(size_t)n * 64 + t] = (t < DIN) ? f2h(a) : (unsigned short)0;
}

// g = A . h, 8 slices x 128 cols, XCD-pinned (measured-best agg variant; further
// slicing refinements were neutral/negative in rounds 10/14/15 — latency/L3-floor)
__global__ __launch_bounds__(256) void agg_slice_kernel(const unsigned short* __restrict__ h,
                                                        const int* __restrict__ offs,
                                                        const int* __restrict__ csr_src,
                                                        const float* __restrict__ csr_w,
                                                        unsigned short* __restrict__ g) {
    const int f = blockIdx.x;
    const int slice = f & 7;
    const int nb = f >> 3;
    const int tid = threadIdx.x;
    const int n = nb * 16 + (tid >> 4);
    const int coloff = slice * 128 + (tid & 15) * 8;
    const unsigned short* hp = h + coloff;

    float a[8] = {0, 0, 0, 0, 0, 0, 0, 0};
    int p0 = offs[n], p1 = offs[n + 1];
    for (int p = p0; p < p1; ++p) {
        int s = csr_src[p];
        float w = csr_w[p];
        uint4 v = *(const uint4*)&hp[(size_t)s * HID];
        const unsigned short* vs = (const unsigned short*)&v;
#pragma unroll
        for (int j = 0; j < 8; ++j) a[j] = fmaf(w, h2f(vs[j]), a[j]);
    }
    unsigned short ov[8];
#pragma unroll
    for (int j = 0; j < 8; ++j) ov[j] = f2h(a[j]);
    *(uint4*)&g[(size_t)n * HID + coloff] = *(const uint4*)ov;
}

// layer-3 final: out[n][c] = sum_p w_p * Q[src_p][c] + Q[n][121+c]  (Q fp16 [N][242])
__global__ __launch_bounds__(256) void agg3_kernel(const unsigned short* __restrict__ Q,
                                                   const int* __restrict__ offs,
                                                   const int* __restrict__ csr_src,
                                                   const float* __restrict__ csr_w,
                                                   float* __restrict__ out) {
    int n = blockIdx.x * 2 + (threadIdx.x >> 7);
    int c = threadIdx.x & 127;
    if (c >= NCLS) return;
    float a = 0.0f;
    int p0 = offs[n], p1 = offs[n + 1];
    for (int p = p0; p < p1; ++p) {
        a = fmaf(csr_w[p], h2f(Q[(size_t)csr_src[p] * NQ + c]), a);
    }
    a += h2f(Q[(size_t)n * NQ + NCLS + c]);
    out[(size_t)n * NCLS + c] = a;
}

// ---------------- fp16 MFMA GEMM: dbuf async pipeline + XOR-swizzled LDS + XCD grouping ----
// Round-12 block order (measured best: 130 us / MfmaUtil 28% / FETCH 72.9 MB / 0 conflicts).
// Used for layer 1 (K=64, write-bound) and layer 3 (small N, grid needs the 128-tile density).
// EPI 0: elu -> fp16 Co. EPI 1: fp32 atomicAdd (unused here). EPI 2: plain fp16 Co.

#define GBM 128
#define GBN 128
#define GBK 32

template <int EPI>
__global__ __launch_bounds__(256, 4) void mfma_gemm_kernel(
        const unsigned short* __restrict__ Ag, const unsigned short* __restrict__ Ah,
        const unsigned short* __restrict__ Bt,
        void* __restrict__ Co,
        int M, int N, int ldc, int ktot, int khalf, int kw,
        int NB, int MB, int mchunk) {
    __shared__ __align__(16) unsigned short sA[2][GBM * GBK];
    __shared__ __align__(16) unsigned short sB[2][GBN * GBK];

    // --- XCD-grouped block swizzle (round-12 order) ---
    const int f = blockIdx.x;
    const int xcd = f & 7;
    const int r0 = f >> 3;
    const int nB = r0 % NB;
    const int mi = r0 / NB;
    const int mB = xcd * mchunk + mi;
    if (mB >= MB) return;
    const int bm = mB * GBM;
    const int bn = nB * GBN;
    const int ks = blockIdx.y;

    const int tid = threadIdx.x;
    const int lane = tid & 63;
    const int wave = tid >> 6;
    const int wm = wave >> 1;
    const int wn = wave & 1;

    // staging map: thread t covers row (t>>2)+64p; stored chunk slot t&3;
    // global chunk = (t&3) ^ ((row>>1)&3).
    const int st_r = tid >> 2;
    const int st_slot = tid & 3;
    const int st_c = (st_slot ^ ((st_r >> 1) & 3)) * 8;
    const int st_lds = st_r * GBK + st_slot * 8;

    int agm[2], bgn[2];
#pragma unroll
    for (int p = 0; p < 2; ++p) {
        int gm = bm + st_r + p * 64;
        agm[p] = gm < M ? gm : M - 1;
        int gn = bn + st_r + p * 64;
        bgn[p] = gn < N ? gn : N - 1;
    }

    const int frow = lane & 15;
    const int fkc = (((lane >> 4) ^ ((frow >> 1) & 3))) * 8;

    floatx4 acc[4][4];
#pragma unroll
    for (int i = 0; i < 4; ++i)
#pragma unroll
        for (int j = 0; j < 4; ++j) acc[i][j] = (floatx4){0.f, 0.f, 0.f, 0.f};

    auto issue = [&](int k0, int buf) {
        const unsigned short* ap = (k0 < khalf) ? Ag : Ah;
        int ka = (k0 < khalf) ? k0 : k0 - khalf;
#pragma unroll
        for (int p = 0; p < 2; ++p) {
            async16(&ap[(size_t)agm[p] * khalf + ka + st_c],
                    &sA[buf][p * 64 * GBK + st_lds]);
            async16(&Bt[(size_t)bgn[p] * ktot + k0 + st_c],
                    &sB[buf][p * 64 * GBK + st_lds]);
        }
    };

    const int tw = kw / GBK;
    const int t0 = ks * tw;
    const int t1 = t0 + tw;

    issue(t0 * GBK, 0);

    for (int t = t0; t < t1; ++t) {
        __syncthreads();  // drains DMA for tile t (issued one compute-phase ago)
        if (t + 1 < t1) issue((t + 1) * GBK, (t + 1) & 1);

        const unsigned short* a_base = sA[t & 1];
        const unsigned short* b_base = sB[t & 1];
        half8 fa[4], fb[4];
#pragma unroll
        for (int i = 0; i < 4; ++i)
            fa[i] = *(const half8*)&a_base[(wm * 64 + i * 16 + frow) * GBK + fkc];
#pragma unroll
        for (int j = 0; j < 4; ++j)
            fb[j] = *(const half8*)&b_base[(wn * 64 + j * 16 + frow) * GBK + fkc];
#pragma unroll
        for (int i = 0; i < 4; ++i)
#pragma unroll
            for (int j = 0; j < 4; ++j)
                acc[i][j] = __builtin_amdgcn_mfma_f32_16x16x32_f16(fa[i], fb[j], acc[i][j], 0, 0, 0);
    }

    // C/D layout: col=lane&15, row=(lane>>4)*4+reg
    const int c_r0 = (lane >> 4) * 4;
    const int c_c = lane & 15;
#pragma unroll
    for (int i = 0; i < 4; ++i)
#pragma unroll
        for (int j = 0; j < 4; ++j) {
            int gn = bn + wn * 64 + j * 16 + c_c;
            if (gn >= N) continue;
#pragma unroll
            for (int r = 0; r < 4; ++r) {
                int gm = bm + wm * 64 + i * 16 + c_r0 + r;
                if (gm >= M) continue;
                float v = acc[i][j][r];
                if (EPI == 0) {
                    v = v > 0 ? v : expf(v) - 1.0f;  // elu
                    ((unsigned short*)Co)[(size_t)gm * ldc + gn] = f2h(v);
                } else if (EPI == 1) {
                    atomicAdd(&((float*)Co)[(size_t)gm * ldc + gn], v);
                } else {
                    ((unsigned short*)Co)[(size_t)gm * ldc + gn] = f2h(v);
                }
            }
        }
}

// ---------------- layer-2 GEMM: 256x256 minimal-barrier dbuf schedule ----
// Round-1 lesson: 8 lockstep barriers/K-tile serialize LDS-read windows against MFMA
// windows (38% per-block MfmaUtil). Only the two DMA-completion gates are semantically
// required; everything else is left to compiler lgkmcnt scheduling + natural wave drift.
// Per K-tile: 2 regions x {stage 2 pairs; ds_reads; 32 MFMA} with vmcnt(4)/vmcnt(2) gates.
// Stage order: S1=B rows 0-127, S2=B rows 128-255, S3=A rounds {0,2}, S4=A rounds {1,3}.
// In-flight invariant at region tops: {S4(t)} = 2 loads; mid: {S4(t),S1,S2(t+1)} wait->4;
// end: {S1..S4(t+1)} wait->2 (S1,S2,S3(t+1) landed for next half-1).

#define BM8 256
#define BN8 256
#define BK8 64

__global__ __launch_bounds__(512, 2) void gemm8p_kernel(
        const unsigned short* __restrict__ Ag, const unsigned short* __restrict__ Ah,
        const unsigned short* __restrict__ Bt,
        unsigned short* __restrict__ Co,
        int M, int N, int ldc, int ktot, int khalf, int NBn) {
    __shared__ __align__(16) unsigned short sA[2][BM8 * BK8];
    __shared__ __align__(16) unsigned short sB[2][BN8 * BK8];

    // bijective XCD-aware swizzle (m204 variant; nwg=316 is not a multiple of 8)
    const int nwg = gridDim.x;
    const int orig = blockIdx.x;
    const int q = nwg >> 3, r = nwg & 7;
    const int xcd = orig & 7;
    const int wg = (xcd < r ? xcd * (q + 1) : r * (q + 1) + (xcd - r) * q) + (orig >> 3);
    const int mB = wg / NBn;
    const int nB = wg - mB * NBn;   // consecutive wg share the same A M-panel (L2 reuse)
    const int bm = mB * BM8;
    const int bn = nB * BN8;

    const int tid = threadIdx.x;
    const int lane = tid & 63;
    const int wave = tid >> 6;
    const int wm = wave >> 2;       // 0..1 : M half (128 rows)
    const int wn = wave & 3;        // 0..3 : N quarter (64 cols)

    // staging map: thread covers LDS row srow (+64*round), 16B chunk sslot; LDS-linear dest.
    const int srow = tid >> 3;      // 0..63
    const int sslot = tid & 7;
    const int swcol = (sslot ^ (srow & 7)) * 8;     // pre-swizzled source column (halfs)
    const int ldso = srow * BK8 + sslot * 8;        // halfs within a 64-row round

    size_t aoff[4], boff[4];
#pragma unroll
    for (int rr = 0; rr < 4; ++rr) {
        int gm = bm + rr * 64 + srow; if (gm >= M) gm = M - 1;
        aoff[rr] = (size_t)gm * khalf + swcol;
        int gn = bn + rr * 64 + srow; if (gn >= N) gn = N - 1;
        boff[rr] = (size_t)gn * ktot + swcol;
    }

    auto stage_b = [&](int t, int h) {
        const int k0 = t * BK8;
        unsigned short* dst = sB[t & 1];
        async16(Bt + boff[2 * h] + k0,     dst + (2 * h) * 64 * BK8 + ldso);
        async16(Bt + boff[2 * h + 1] + k0, dst + (2 * h + 1) * 64 * BK8 + ldso);
    };
    auto stage_a = [&](int t, int w) {
        const int k0 = t * BK8;
        const unsigned short* ap = (k0 < khalf) ? Ag : Ah;
        const int ka = (k0 < khalf) ? k0 : k0 - khalf;
        unsigned short* dst = sA[t & 1];
        async16(ap + aoff[w] + ka,     dst + w * 64 * BK8 + ldso);
        async16(ap + aoff[w + 2] + ka, dst + (w + 2) * 64 * BK8 + ldso);
    };

    floatx4 acc[8][4];
#pragma unroll
    for (int i = 0; i < 8; ++i)
#pragma unroll
        for (int j = 0; j < 4; ++j) acc[i][j] = (floatx4){0.f, 0.f, 0.f, 0.f};

    const int NT = ktot / BK8;
    const int frow = lane & 15;
    const int fgrp = lane >> 4;
    const int coff0 = ((fgrp)     ^ (frow & 7)) * 8;   // k-sub 0 phys chunk (halfs)
    const int coff1 = ((4 + fgrp) ^ (frow & 7)) * 8;   // k-sub 1 phys chunk

    // prologue: stage tile 0 fully; wait for S1,S2,S3 (keep S4 in flight).
    stage_b(0, 0); stage_b(0, 1); stage_a(0, 0); stage_a(0, 1);
    asm volatile("s_waitcnt vmcnt(2)" ::: "memory");
    __builtin_amdgcn_s_barrier();

    for (int t = 0; t < NT; ++t) {
        const unsigned short* ab = sA[t & 1];
        const unsigned short* bb = sB[t & 1];
        const bool pf = (t + 1 < NT);
        half8 fa[4][2], fb[4][2];

        // ---- region 1: stage S1,S2(t+1); read fb[0..3] + fa rounds {0,2}; MFMA Q0 (32)
        if (pf) { stage_b(t + 1, 0); stage_b(t + 1, 1); }
#pragma unroll
        for (int j = 0; j < 4; ++j) {
            fb[j][0] = *(const half8*)&bb[(wn * 64 + j * 16 + frow) * BK8 + coff0];
            fb[j][1] = *(const half8*)&bb[(wn * 64 + j * 16 + frow) * BK8 + coff1];
        }
#pragma unroll
        for (int i = 0; i < 4; ++i) {
            fa[i][0] = *(const half8*)&ab[(wm * 128 + i * 16 + frow) * BK8 + coff0];
            fa[i][1] = *(const half8*)&ab[(wm * 128 + i * 16 + frow) * BK8 + coff1];
        }
        __builtin_amdgcn_s_setprio(1);
#pragma unroll
        for (int kk = 0; kk < 2; ++kk)
#pragma unroll
            for (int i = 0; i < 4; ++i)
#pragma unroll
                for (int j = 0; j < 4; ++j)
                    acc[i][j] = __builtin_amdgcn_mfma_f32_16x16x32_f16(fa[i][kk], fb[j][kk], acc[i][j], 0, 0, 0);
        __builtin_amdgcn_s_setprio(0);
        // gate: S4(t) landed before any wave reads A rounds {1,3} of buffer t
        if (pf) { asm volatile("s_waitcnt vmcnt(4)" ::: "memory"); }
        else    { asm volatile("s_waitcnt vmcnt(0)" ::: "memory"); }
        __builtin_amdgcn_s_barrier();

        // ---- region 2: stage S3,S4(t+1); read fa rounds {1,3}; MFMA Q1 (32)
        if (pf) { stage_a(t + 1, 0); stage_a(t + 1, 1); }
#pragma unroll
        for (int i = 0; i < 4; ++i) {
            fa[i][0] = *(const half8*)&ab[(wm * 128 + 64 + i * 16 + frow) * BK8 + coff0];
            fa[i][1] = *(const half8*)&ab[(wm * 128 + 64 + i * 16 + frow) * BK8 + coff1];
        }
        __builtin_amdgcn_s_setprio(1);
#pragma unroll
        for (int kk = 0; kk < 2; ++kk)
#pragma unroll
            for (int i = 0; i < 4; ++i)
#pragma unroll
                for (int j = 0; j < 4; ++j)
                    acc[4 + i][j] = __builtin_amdgcn_mfma_f32_16x16x32_f16(fa[i][kk], fb[j][kk], acc[4 + i][j], 0, 0, 0);
        __builtin_amdgcn_s_setprio(0);
        // gate: S1,S2,S3(t+1) landed before next region-1 reads buffer t+1
        if (pf) {
            asm volatile("s_waitcnt vmcnt(2)" ::: "memory");
            __builtin_amdgcn_s_barrier();
        }
    }

    // epilogue: elu -> fp16.  C/D layout: col=lane&15, row=(lane>>4)*4+reg
    const int c_c = lane & 15;
    const int c_r0 = fgrp * 4;
#pragma unroll
    for (int i = 0; i < 8; ++i)
#pragma unroll
        for (int j = 0; j < 4; ++j) {
            const int gn = bn + wn * 64 + j * 16 + c_c;
            if (gn >= N) continue;
#pragma unroll
            for (int rr = 0; rr < 4; ++rr) {
                const int gm = bm + wm * 128 + i * 16 + c_r0 + rr;
                if (gm >= M) continue;
                float v = acc[i][j][rr];
                v = v > 0 ? v : expf(v) - 1.0f;  // elu
                Co[(size_t)gm * ldc + gn] = f2h(v);
            }
        }
}

// ---------------- launch ----------------

static inline size_t align_up(size_t x, size_t a) { return (x + a - 1) & ~(a - 1); }

extern "C" void kernel_launch(void* const* d_in, const int* in_sizes, int n_in,
                              void* d_out, int out_size, void* d_ws, size_t ws_size,
                              hipStream_t stream) {
    const float* X  = (const float*)d_in[0];
    const int* erow = (const int*)d_in[1];
    const int* ecol = (const int*)d_in[1] + N_EDGES;
    const float* W1 = (const float*)d_in[2];
    const float* W2 = (const float*)d_in[3];
    const float* S2 = (const float*)d_in[4];
    const float* W3 = (const float*)d_in[5];
    const float* S3 = (const float*)d_in[6];
    float* out = (float*)d_out;

    // workspace carve-up
    char* w = (char*)d_ws;
    int* deg     = (int*)w;             w += align_up((size_t)N_NODES * 4, 256);
    int* offs    = (int*)w;             w += align_up((size_t)(N_NODES + 1) * 4, 256);
    int* cursor  = (int*)w;             w += align_up((size_t)N_NODES * 4, 256);
    int* csr_src = (int*)w;             w += align_up((size_t)N_EDGES * 4, 256);
    float* dis   = (float*)w;           w += align_up((size_t)N_NODES * 4, 256);
    float* csr_w = (float*)w;           w += align_up((size_t)N_EDGES * 4, 256);
    unsigned short* gXh = (unsigned short*)w; w += align_up((size_t)N_NODES * 64 * 2, 256);
    unsigned short* h1 = (unsigned short*)w;  w += align_up((size_t)N_NODES * HID * 2, 256);
    unsigned short* g  = (unsigned short*)w;  w += align_up((size_t)N_NODES * HID * 2, 256);
    unsigned short* h2 = (unsigned short*)w;  w += align_up((size_t)N_NODES * HID * 2, 256);
    unsigned short* Qh = (unsigned short*)w;  w += align_up((size_t)N_NODES * NQ * 2, 256);
    unsigned short* Bt1 = (unsigned short*)w; w += align_up((size_t)HID * 64 * 2, 256);
    unsigned short* Bt2 = (unsigned short*)w; w += align_up((size_t)HID * KCAT * 2, 256);
    unsigned short* Bt3 = (unsigned short*)w; w += align_up((size_t)NQ * HID * 2, 256);

    const int TB = 256;
    int nb_n = (N_NODES + TB - 1) / TB;

    // 1. zero deg; 2. merged prep (count_deg + all weight prep)
    zero_int_kernel<<<nb_n, TB, 0, stream>>>(deg, N_NODES);
    prep_kernel<<<3810, 256, 0, stream>>>(ecol, deg, W1, Bt1, W2, S2, Bt2, W3, S3, Bt3);

    // 3. scan; 4. scatter
    scan_kernel<<<1, 1024, 0, stream>>>(deg, offs, cursor, dis, N_NODES, N_EDGES);
    scatter_kernel<<<(N_EDGES + TB - 1) / TB, TB, 0, stream>>>(erow, ecol, dis, cursor,
                                                               csr_src, csr_w, N_EDGES);

    const int MB = (N_NODES + GBM - 1) / GBM;   // 157
    const int mchunk = (MB + 7) / 8;            // 20
    const int NB2 = HID / GBN;                  // 8
    const int NB3 = (NQ + GBN - 1) / GBN;       // 2
    const int AGG_GRID = 8 * (N_NODES / 16);    // 8 slices x 1250 node-blocks

    const int MB8 = (N_NODES + BM8 - 1) / BM8;  // 79
    const int NB8 = HID / BN8;                  // 4

    // 5-6. layer 1: gX = A.X ; h1 = elu(gX @ W1)   (K=64, write-bound -> 128-tile kernel)
    aggX_kernel<<<N_NODES, 64, 0, stream>>>(X, offs, csr_src, csr_w, gXh);
    mfma_gemm_kernel<0><<<dim3(8 * mchunk * NB2, 1), 256, 0, stream>>>(
        gXh, gXh, Bt1, h1, N_NODES, HID, HID, 64, 64, 64, NB2, MB, mchunk);

    // 7-8. layer 2: g1 = A.h1 ; h2 = elu([g1|h1] @ [W2;S2])  (minimal-barrier 256x256 kernel)
    agg_slice_kernel<<<AGG_GRID, 256, 0, stream>>>(h1, offs, csr_src, csr_w, g);
    gemm8p_kernel<<<dim3(MB8 * NB8), 512, 0, stream>>>(
        g, h1, Bt2, h2, N_NODES, HID, HID, KCAT, HID, NB8);

    // 9-10. layer 3 (project-then-aggregate): Q = h2 @ [W3bar|S3bar] (fp16);
    //        out = agg(Q_w) + Q_s
    mfma_gemm_kernel<2><<<dim3(8 * mchunk * NB3, 1), 256, 0, stream>>>(
        h2, h2, Bt3, Qh, N_NODES, NQ, NQ, HID, HID, HID, NB3, MB, mchunk);
    agg3_kernel<<<N_NODES / 2, 256, 0, stream>>>(Qh, offs, csr_src, csr_w, out);
}

// Round 3
// 451.881 us; speedup vs baseline: 1.1872x; 1.1872x over previous
//
#include <hip/hip_runtime.h>
#include <hip/hip_bf16.h>
#include <math.h>

#define N_NODES 20000
#define N_EDGES 320000
#define DIN 50
#define HID 1024
#define NC3 726   // 6*121
#define NCLS 121
#define KCAT 2048
#define NQP 256   // padded [W3bar(128) | S3bar(128)] projected width (16B-aligned rows)

typedef __attribute__((ext_vector_type(8))) _Float16 half8;
typedef __attribute__((ext_vector_type(4))) float floatx4;

__device__ __forceinline__ unsigned short f2h(float v) {
    _Float16 h = (_Float16)v;
    return __builtin_bit_cast(unsigned short, h);
}
__device__ __forceinline__ float h2f(unsigned short u) {
    return (float)__builtin_bit_cast(_Float16, u);
}

// async global->LDS, 16B per lane. LDS dest must equal wave-uniform base + lane*16.
__device__ __forceinline__ void async16(const void* g, void* l) {
    __builtin_amdgcn_global_load_lds(
        (const __attribute__((address_space(1))) void*)g,
        (__attribute__((address_space(3))) void*)l,
        16, 0, 0);
}

// ---------------- CSR build ----------------

__global__ void zero_int_kernel(int* p, int n) {
    int i = blockIdx.x * blockDim.x + threadIdx.x;
    if (i < n) p[i] = 0;
}

// exclusive scan of deg -> offs/cursor; also emits dis = deg^-1/2
__global__ __launch_bounds__(1024) void scan_kernel(const int* __restrict__ deg,
                                                    int* __restrict__ offs,
                                                    int* __restrict__ cursor,
                                                    float* __restrict__ dis,
                                                    int n, int total) {
    __shared__ int part[1024];
    int t = threadIdx.x;
    const int CH = (n + 1023) / 1024;
    int base0 = t * CH;
    int s = 0;
    for (int i = 0; i < CH; ++i) {
        int idx = base0 + i;
        if (idx < n) s += deg[idx];
    }
    part[t] = s;
    __syncthreads();
    for (int d = 1; d < 1024; d <<= 1) {
        int v = (t >= d) ? part[t - d] : 0;
        __syncthreads();
        part[t] += v;
        __syncthreads();
    }
    int run = part[t] - s;
    for (int i = 0; i < CH; ++i) {
        int idx = base0 + i;
        if (idx < n) {
            int d = deg[idx];
            offs[idx] = run;
            cursor[idx] = run;
            dis[idx] = d > 0 ? rsqrtf((float)d) : 0.0f;
            run += d;
        }
    }
    if (t == 1023) offs[n] = total;
}

// scatter with inline norm = dis[row]*dis[col]
__global__ void scatter_kernel(const int* __restrict__ row, const int* __restrict__ col,
                               const float* __restrict__ dis, int* __restrict__ cursor,
                               int* __restrict__ csr_src, float* __restrict__ csr_w, int e) {
    int i = blockIdx.x * blockDim.x + threadIdx.x;
    if (i < e) {
        int r = row[i], c = col[i];
        float nm = dis[r] * dis[c];
        int pos = atomicAdd(&cursor[c], 1);
        csr_src[pos] = r;
        csr_w[pos] = nm;
    }
}

// ---------------- merged prep: count_deg + w1t + wt2 transpose + wt3 fold+transpose ----
// blockIdx ranges:  [0,2048) wt2 | [2048,2304) wt3 | [2304,2560) w1t | [2560,3810) count_deg
__global__ __launch_bounds__(256) void prep_kernel(const int* __restrict__ ecol,
                                                   int* __restrict__ deg,
                                                   const float* __restrict__ W1,
                                                   unsigned short* __restrict__ Bt1,
                                                   const float* __restrict__ W2,
                                                   const float* __restrict__ S2,
                                                   unsigned short* __restrict__ Bt2,
                                                   const float* __restrict__ W3,
                                                   const float* __restrict__ S3,
                                                   unsigned short* __restrict__ Bt3) {
    __shared__ unsigned short tile[32][33];
    const int b = blockIdx.x;
    const int tid = threadIdx.x;

    if (b < 2048) {
        // W2/S2 [1024][1024] -> Bt2 fp16 [1024][2048] transposed via LDS 32x32 tiles
        int src = b >> 10;
        int t = b & 1023;
        int k0 = (t >> 5) * 32;
        int n0 = (t & 31) * 32;
        const float* W = src ? S2 : W2;
        int koff = src ? HID : 0;
        int tx = tid & 31;
        int ty = tid >> 5;
#pragma unroll
        for (int r = 0; r < 32; r += 8)
            tile[ty + r][tx] = f2h(W[(size_t)(k0 + ty + r) * HID + n0 + tx]);
        __syncthreads();
#pragma unroll
        for (int r = 0; r < 32; r += 8)
            Bt2[(size_t)(n0 + ty + r) * KCAT + koff + k0 + tx] = tile[tx][ty + r];
    } else if (b < 2304) {
        // W3/S3 [1024][726] -> head-mean + transpose -> Bt3 fp16 [2*128][1024] (pad rows 0)
        int tb = b - 2048;
        int src = tb >> 7;
        int t = tb & 127;
        int k0 = (t >> 2) * 32;
        int c0 = (t & 3) * 32;
        const float* W = src ? S3 : W3;
        int tx = tid & 31;
        int ty = tid >> 5;
#pragma unroll
        for (int r = 0; r < 32; r += 8) {
            int k = k0 + ty + r, c = c0 + tx;
            float v = 0.0f;
            if (c < NCLS) {
                const float* p = W + (size_t)k * NC3 + c;
                v = (p[0] + p[121] + p[242] + p[363] + p[484] + p[605]) * (1.0f / 6.0f);
            }
            tile[ty + r][tx] = f2h(v);
        }
        __syncthreads();
#pragma unroll
        for (int r = 0; r < 32; r += 8) {
            int c = c0 + ty + r;   // always < 128; pad cols carry 0 so Qh pads are defined
            Bt3[(size_t)(src * 128 + c) * HID + k0 + tx] = tile[tx][ty + r];
        }
    } else if (b < 2560) {
        // W1 [50][1024] -> Bt1 fp16 [1024][64] transposed, padded
        int i = (b - 2304) * 256 + tid;
        int n = i / 64, k = i - n * 64;
        Bt1[i] = (k < DIN) ? f2h(W1[(size_t)k * HID + n]) : (unsigned short)0;
    } else {
        // degree count
        int i = (b - 2560) * 256 + tid;
        if (i < N_EDGES) atomicAdd(&deg[ecol[i]], 1);
    }
}

// ---------------- aggregations ----------------

// gX = A . X  (50-wide fp32 gather -> fp16 out, rows padded to 64)
__global__ __launch_bounds__(64) void aggX_kernel(const float* __restrict__ X,
                                                  const int* __restrict__ offs,
                                                  const int* __restrict__ csr_src,
                                                  const float* __restrict__ csr_w,
                                                  unsigned short* __restrict__ gX) {
    int n = blockIdx.x;
    int t = threadIdx.x;
    float a = 0.0f;
    if (t < DIN) {
        int p0 = offs[n], p1 = offs[n + 1];
        for (int p = p0; p < p1; ++p) {
            a = fmaf(csr_w[p], X[(size_t)csr_src[p] * DIN + t], a);
        }
    }
    gX[(size_t)n * 64 + t] = (t < DIN) ? f2h(a) : (unsigned short)0;
}

// g = A . h, 8 slices x 128 cols, XCD-pinned (measured-best agg variant; further
// slicing refinements were neutral/negative in rounds 10/14/15 — latency/L3-floor)
__global__ __launch_bounds__(256) void agg_slice_kernel(const unsigned short* __restrict__ h,
                                                        const int* __restrict__ offs,
                                                        const int* __restrict__ csr_src,
                                                        const float* __restrict__ csr_w,
                                                        unsigned short* __restrict__ g) {
    const int f = blockIdx.x;
    const int slice = f & 7;
    const int nb = f >> 3;
    const int tid = threadIdx.x;
    const int n = nb * 16 + (tid >> 4);
    const int coloff = slice * 128 + (tid & 15) * 8;
    const unsigned short* hp = h + coloff;

    float a[8] = {0, 0, 0, 0, 0, 0, 0, 0};
    int p0 = offs[n], p1 = offs[n + 1];
    for (int p = p0; p < p1; ++p) {
        int s = csr_src[p];
        float w = csr_w[p];
        uint4 v = *(const uint4*)&hp[(size_t)s * HID];
        const unsigned short* vs = (const unsigned short*)&v;
#pragma unroll
        for (int j = 0; j < 8; ++j) a[j] = fmaf(w, h2f(vs[j]), a[j]);
    }
    unsigned short ov[8];
#pragma unroll
    for (int j = 0; j < 8; ++j) ov[j] = f2h(a[j]);
    *(uint4*)&g[(size_t)n * HID + coloff] = *(const uint4*)ov;
}

// layer-3 final, vectorized: 16 lanes/node x 8 cols via uint4 (Q fp16 [N][256]).
// Round-2 change: was 121 scalar 2B loads/edge (38.7M loads, issue-bound ~60us);
// now 16 uint4 loads/edge. out[n][c] = sum_p w_p * Q[src_p][c] + Q[n][128+c].
__global__ __launch_bounds__(256) void agg3_kernel(const unsigned short* __restrict__ Q,
                                                   const int* __restrict__ offs,
                                                   const int* __restrict__ csr_src,
                                                   const float* __restrict__ csr_w,
                                                   float* __restrict__ out) {
    const int n = blockIdx.x * 16 + (threadIdx.x >> 4);
    const int c0 = (threadIdx.x & 15) * 8;
    float a[8] = {0, 0, 0, 0, 0, 0, 0, 0};
    const int p0 = offs[n], p1 = offs[n + 1];
    for (int p = p0; p < p1; ++p) {
        const float w = csr_w[p];
        uint4 v = *(const uint4*)&Q[(size_t)csr_src[p] * NQP + c0];
        const unsigned short* vs = (const unsigned short*)&v;
#pragma unroll
        for (int j = 0; j < 8; ++j) a[j] = fmaf(w, h2f(vs[j]), a[j]);
    }
    uint4 sv = *(const uint4*)&Q[(size_t)n * NQP + 128 + c0];
    const unsigned short* ss = (const unsigned short*)&sv;
#pragma unroll
    for (int j = 0; j < 8; ++j) {
        int c = c0 + j;
        if (c < NCLS) out[(size_t)n * NCLS + c] = a[j] + h2f(ss[j]);
    }
}

// ---------------- fp16 MFMA GEMM: dbuf async pipeline + XOR-swizzled LDS + XCD grouping ----
// Proven 128x128 structure (130 us on layer 2 / MfmaUtil 28% / 0 conflicts). Rounds 1-2
// established the 256x256 low-occupancy schedule cannot beat it on this shape (148/180 us):
// at 2 waves/SIMD the inter-block drift overlap (4 blocks/CU here) is structurally absent.
// EPI 0: elu -> fp16 Co. EPI 1: fp32 atomicAdd (unused here). EPI 2: plain fp16 Co.

#define GBM 128
#define GBN 128
#define GBK 32

template <int EPI>
__global__ __launch_bounds__(256, 4) void mfma_gemm_kernel(
        const unsigned short* __restrict__ Ag, const unsigned short* __restrict__ Ah,
        const unsigned short* __restrict__ Bt,
        void* __restrict__ Co,
        int M, int N, int ldc, int ktot, int khalf, int kw,
        int NB, int MB, int mchunk) {
    __shared__ __align__(16) unsigned short sA[2][GBM * GBK];
    __shared__ __align__(16) unsigned short sB[2][GBN * GBK];

    // --- XCD-grouped block swizzle (round-12 order) ---
    const int f = blockIdx.x;
    const int xcd = f & 7;
    const int r0 = f >> 3;
    const int nB = r0 % NB;
    const int mi = r0 / NB;
    const int mB = xcd * mchunk + mi;
    if (mB >= MB) return;
    const int bm = mB * GBM;
    const int bn = nB * GBN;
    const int ks = blockIdx.y;

    const int tid = threadIdx.x;
    const int lane = tid & 63;
    const int wave = tid >> 6;
    const int wm = wave >> 1;
    const int wn = wave & 1;

    // staging map: thread t covers row (t>>2)+64p; stored chunk slot t&3;
    // global chunk = (t&3) ^ ((row>>1)&3).
    const int st_r = tid >> 2;
    const int st_slot = tid & 3;
    const int st_c = (st_slot ^ ((st_r >> 1) & 3)) * 8;
    const int st_lds = st_r * GBK + st_slot * 8;

    int agm[2], bgn[2];
#pragma unroll
    for (int p = 0; p < 2; ++p) {
        int gm = bm + st_r + p * 64;
        agm[p] = gm < M ? gm : M - 1;
        int gn = bn + st_r + p * 64;
        bgn[p] = gn < N ? gn : N - 1;
    }

    const int frow = lane & 15;
    const int fkc = (((lane >> 4) ^ ((frow >> 1) & 3))) * 8;

    floatx4 acc[4][4];
#pragma unroll
    for (int i = 0; i < 4; ++i)
#pragma unroll
        for (int j = 0; j < 4; ++j) acc[i][j] = (floatx4){0.f, 0.f, 0.f, 0.f};

    auto issue = [&](int k0, int buf) {
        const unsigned short* ap = (k0 < khalf) ? Ag : Ah;
        int ka = (k0 < khalf) ? k0 : k0 - khalf;
#pragma unroll
        for (int p = 0; p < 2; ++p) {
            async16(&ap[(size_t)agm[p] * khalf + ka + st_c],
                    &sA[buf][p * 64 * GBK + st_lds]);
            async16(&Bt[(size_t)bgn[p] * ktot + k0 + st_c],
                    &sB[buf][p * 64 * GBK + st_lds]);
        }
    };

    const int tw = kw / GBK;
    const int t0 = ks * tw;
    const int t1 = t0 + tw;

    issue(t0 * GBK, 0);

    for (int t = t0; t < t1; ++t) {
        __syncthreads();  // drains DMA for tile t (issued one compute-phase ago)
        if (t + 1 < t1) issue((t + 1) * GBK, (t + 1) & 1);

        const unsigned short* a_base = sA[t & 1];
        const unsigned short* b_base = sB[t & 1];
        half8 fa[4], fb[4];
#pragma unroll
        for (int i = 0; i < 4; ++i)
            fa[i] = *(const half8*)&a_base[(wm * 64 + i * 16 + frow) * GBK + fkc];
#pragma unroll
        for (int j = 0; j < 4; ++j)
            fb[j] = *(const half8*)&b_base[(wn * 64 + j * 16 + frow) * GBK + fkc];
#pragma unroll
        for (int i = 0; i < 4; ++i)
#pragma unroll
            for (int j = 0; j < 4; ++j)
                acc[i][j] = __builtin_amdgcn_mfma_f32_16x16x32_f16(fa[i], fb[j], acc[i][j], 0, 0, 0);
    }

    // C/D layout: col=lane&15, row=(lane>>4)*4+reg
    const int c_r0 = (lane >> 4) * 4;
    const int c_c = lane & 15;
#pragma unroll
    for (int i = 0; i < 4; ++i)
#pragma unroll
        for (int j = 0; j < 4; ++j) {
            int gn = bn + wn * 64 + j * 16 + c_c;
            if (gn >= N) continue;
#pragma unroll
            for (int r = 0; r < 4; ++r) {
                int gm = bm + wm * 64 + i * 16 + c_r0 + r;
                if (gm >= M) continue;
                float v = acc[i][j][r];
                if (EPI == 0) {
                    v = v > 0 ? v : expf(v) - 1.0f;  // elu
                    ((unsigned short*)Co)[(size_t)gm * ldc + gn] = f2h(v);
                } else if (EPI == 1) {
                    atomicAdd(&((float*)Co)[(size_t)gm * ldc + gn], v);
                } else {
                    ((unsigned short*)Co)[(size_t)gm * ldc + gn] = f2h(v);
                }
            }
        }
}

// ---------------- launch ----------------

static inline size_t align_up(size_t x, size_t a) { return (x + a - 1) & ~(a - 1); }

extern "C" void kernel_launch(void* const* d_in, const int* in_sizes, int n_in,
                              void* d_out, int out_size, void* d_ws, size_t ws_size,
                              hipStream_t stream) {
    const float* X  = (const float*)d_in[0];
    const int* erow = (const int*)d_in[1];
    const int* ecol = (const int*)d_in[1] + N_EDGES;
    const float* W1 = (const float*)d_in[2];
    const float* W2 = (const float*)d_in[3];
    const float* S2 = (const float*)d_in[4];
    const float* W3 = (const float*)d_in[5];
    const float* S3 = (const float*)d_in[6];
    float* out = (float*)d_out;

    // workspace carve-up
    char* w = (char*)d_ws;
    int* deg     = (int*)w;             w += align_up((size_t)N_NODES * 4, 256);
    int* offs    = (int*)w;             w += align_up((size_t)(N_NODES + 1) * 4, 256);
    int* cursor  = (int*)w;             w += align_up((size_t)N_NODES * 4, 256);
    int* csr_src = (int*)w;             w += align_up((size_t)N_EDGES * 4, 256);
    float* dis   = (float*)w;           w += align_up((size_t)N_NODES * 4, 256);
    float* csr_w = (float*)w;           w += align_up((size_t)N_EDGES * 4, 256);
    unsigned short* gXh = (unsigned short*)w; w += align_up((size_t)N_NODES * 64 * 2, 256);
    unsigned short* h1 = (unsigned short*)w;  w += align_up((size_t)N_NODES * HID * 2, 256);
    unsigned short* g  = (unsigned short*)w;  w += align_up((size_t)N_NODES * HID * 2, 256);
    unsigned short* h2 = (unsigned short*)w;  w += align_up((size_t)N_NODES * HID * 2, 256);
    unsigned short* Qh = (unsigned short*)w;  w += align_up((size_t)N_NODES * NQP * 2, 256);
    unsigned short* Bt1 = (unsigned short*)w; w += align_up((size_t)HID * 64 * 2, 256);
    unsigned short* Bt2 = (unsigned short*)w; w += align_up((size_t)HID * KCAT * 2, 256);
    unsigned short* Bt3 = (unsigned short*)w; w += align_up((size_t)256 * HID * 2, 256);

    const int TB = 256;
    int nb_n = (N_NODES + TB - 1) / TB;

    // 1. zero deg; 2. merged prep (count_deg + all weight prep)
    zero_int_kernel<<<nb_n, TB, 0, stream>>>(deg, N_NODES);
    prep_kernel<<<3810, 256, 0, stream>>>(ecol, deg, W1, Bt1, W2, S2, Bt2, W3, S3, Bt3);

    // 3. scan; 4. scatter
    scan_kernel<<<1, 1024, 0, stream>>>(deg, offs, cursor, dis, N_NODES, N_EDGES);
    scatter_kernel<<<(N_EDGES + TB - 1) / TB, TB, 0, stream>>>(erow, ecol, dis, cursor,
                                                               csr_src, csr_w, N_EDGES);

    const int MB = (N_NODES + GBM - 1) / GBM;   // 157
    const int mchunk = (MB + 7) / 8;            // 20
    const int NB2 = HID / GBN;                  // 8
    const int NB3 = NQP / GBN;                  // 2 (exact, no masking holes)
    const int AGG_GRID = 8 * (N_NODES / 16);    // 8 slices x 1250 node-blocks

    // 5-6. layer 1: gX = A.X ; h1 = elu(gX @ W1)
    aggX_kernel<<<N_NODES, 64, 0, stream>>>(X, offs, csr_src, csr_w, gXh);
    mfma_gemm_kernel<0><<<dim3(8 * mchunk * NB2, 1), 256, 0, stream>>>(
        gXh, gXh, Bt1, h1, N_NODES, HID, HID, 64, 64, 64, NB2, MB, mchunk);

    // 7-8. layer 2: g1 = A.h1 ; h2 = elu([g1|h1] @ [W2;S2])
    agg_slice_kernel<<<AGG_GRID, 256, 0, stream>>>(h1, offs, csr_src, csr_w, g);
    mfma_gemm_kernel<0><<<dim3(8 * mchunk * NB2, 1), 256, 0, stream>>>(
        g, h1, Bt2, h2, N_NODES, HID, HID, KCAT, HID, KCAT, NB2, MB, mchunk);

    // 9-10. layer 3 (project-then-aggregate): Q = h2 @ [W3bar|S3bar] (fp16, padded 256);
    //        out = agg(Q_w) + Q_s
    mfma_gemm_kernel<2><<<dim3(8 * mchunk * NB3, 1), 256, 0, stream>>>(
        h2, h2, Bt3, Qh, N_NODES, NQP, NQP, HID, HID, HID, NB3, MB, mchunk);
    agg3_kernel<<<N_NODES / 16, 256, 0, stream>>>(Qh, offs, csr_src, csr_w, out);
}

// Round 4
// 413.529 us; speedup vs baseline: 1.2973x; 1.0927x over previous
//
#include <hip/hip_runtime.h>
#include <hip/hip_bf16.h>
#include <math.h>

#define N_NODES 20000
#define N_EDGES 320000
#define DIN 50
#define HID 1024
#define NC3 726   // 6*121
#define NCLS 121
#define KCAT 2048
#define NQP 256   // padded [W3bar(128) | S3bar(128)] projected width (16B-aligned rows)

typedef __attribute__((ext_vector_type(8))) _Float16 half8;
typedef __attribute__((ext_vector_type(4))) float floatx4;

__device__ __forceinline__ unsigned short f2h(float v) {
    _Float16 h = (_Float16)v;
    return __builtin_bit_cast(unsigned short, h);
}
__device__ __forceinline__ float h2f(unsigned short u) {
    return (float)__builtin_bit_cast(_Float16, u);
}

// async global->LDS, 16B per lane. LDS dest must equal wave-uniform base + lane*16.
__device__ __forceinline__ void async16(const void* g, void* l) {
    __builtin_amdgcn_global_load_lds(
        (const __attribute__((address_space(1))) void*)g,
        (__attribute__((address_space(3))) void*)l,
        16, 0, 0);
}

// ---------------- CSR build ----------------

__global__ void zero_int_kernel(int* p, int n) {
    int i = blockIdx.x * blockDim.x + threadIdx.x;
    if (i < n) p[i] = 0;
}

// exclusive scan of deg -> offs/cursor; also emits dis = deg^-1/2
__global__ __launch_bounds__(1024) void scan_kernel(const int* __restrict__ deg,
                                                    int* __restrict__ offs,
                                                    int* __restrict__ cursor,
                                                    float* __restrict__ dis,
                                                    int n, int total) {
    __shared__ int part[1024];
    int t = threadIdx.x;
    const int CH = (n + 1023) / 1024;
    int base0 = t * CH;
    int s = 0;
    for (int i = 0; i < CH; ++i) {
        int idx = base0 + i;
        if (idx < n) s += deg[idx];
    }
    part[t] = s;
    __syncthreads();
    for (int d = 1; d < 1024; d <<= 1) {
        int v = (t >= d) ? part[t - d] : 0;
        __syncthreads();
        part[t] += v;
        __syncthreads();
    }
    int run = part[t] - s;
    for (int i = 0; i < CH; ++i) {
        int idx = base0 + i;
        if (idx < n) {
            int d = deg[idx];
            offs[idx] = run;
            cursor[idx] = run;
            dis[idx] = d > 0 ? rsqrtf((float)d) : 0.0f;
            run += d;
        }
    }
    if (t == 1023) offs[n] = total;
}

// scatter with inline norm = dis[row]*dis[col]
__global__ void scatter_kernel(const int* __restrict__ row, const int* __restrict__ col,
                               const float* __restrict__ dis, int* __restrict__ cursor,
                               int* __restrict__ csr_src, float* __restrict__ csr_w, int e) {
    int i = blockIdx.x * blockDim.x + threadIdx.x;
    if (i < e) {
        int r = row[i], c = col[i];
        float nm = dis[r] * dis[c];
        int pos = atomicAdd(&cursor[c], 1);
        csr_src[pos] = r;
        csr_w[pos] = nm;
    }
}

// ---------------- merged prep: count_deg + w1t + wt2 transpose + wt3 fold+transpose ----
// blockIdx ranges:  [0,2048) wt2 | [2048,2304) wt3 | [2304,2560) w1t | [2560,3810) count_deg
__global__ __launch_bounds__(256) void prep_kernel(const int* __restrict__ ecol,
                                                   int* __restrict__ deg,
                                                   const float* __restrict__ W1,
                                                   unsigned short* __restrict__ Bt1,
                                                   const float* __restrict__ W2,
                                                   const float* __restrict__ S2,
                                                   unsigned short* __restrict__ Bt2,
                                                   const float* __restrict__ W3,
                                                   const float* __restrict__ S3,
                                                   unsigned short* __restrict__ Bt3) {
    __shared__ unsigned short tile[32][33];
    const int b = blockIdx.x;
    const int tid = threadIdx.x;

    if (b < 2048) {
        // W2/S2 [1024][1024] -> Bt2 fp16 [1024][2048] transposed via LDS 32x32 tiles
        int src = b >> 10;
        int t = b & 1023;
        int k0 = (t >> 5) * 32;
        int n0 = (t & 31) * 32;
        const float* W = src ? S2 : W2;
        int koff = src ? HID : 0;
        int tx = tid & 31;
        int ty = tid >> 5;
#pragma unroll
        for (int r = 0; r < 32; r += 8)
            tile[ty + r][tx] = f2h(W[(size_t)(k0 + ty + r) * HID + n0 + tx]);
        __syncthreads();
#pragma unroll
        for (int r = 0; r < 32; r += 8)
            Bt2[(size_t)(n0 + ty + r) * KCAT + koff + k0 + tx] = tile[tx][ty + r];
    } else if (b < 2304) {
        // W3/S3 [1024][726] -> head-mean + transpose -> Bt3 fp16 [2*128][1024] (pad rows 0)
        int tb = b - 2048;
        int src = tb >> 7;
        int t = tb & 127;
        int k0 = (t >> 2) * 32;
        int c0 = (t & 3) * 32;
        const float* W = src ? S3 : W3;
        int tx = tid & 31;
        int ty = tid >> 5;
#pragma unroll
        for (int r = 0; r < 32; r += 8) {
            int k = k0 + ty + r, c = c0 + tx;
            float v = 0.0f;
            if (c < NCLS) {
                const float* p = W + (size_t)k * NC3 + c;
                v = (p[0] + p[121] + p[242] + p[363] + p[484] + p[605]) * (1.0f / 6.0f);
            }
            tile[ty + r][tx] = f2h(v);
        }
        __syncthreads();
#pragma unroll
        for (int r = 0; r < 32; r += 8) {
            int c = c0 + ty + r;   // always < 128; pad cols carry 0 so Qh pads are defined
            Bt3[(size_t)(src * 128 + c) * HID + k0 + tx] = tile[tx][ty + r];
        }
    } else if (b < 2560) {
        // W1 [50][1024] -> Bt1 fp16 [1024][64] transposed, padded
        int i = (b - 2304) * 256 + tid;
        int n = i / 64, k = i - n * 64;
        Bt1[i] = (k < DIN) ? f2h(W1[(size_t)k * HID + n]) : (unsigned short)0;
    } else {
        // degree count
        int i = (b - 2560) * 256 + tid;
        if (i < N_EDGES) atomicAdd(&deg[ecol[i]], 1);
    }
}

// ---------------- aggregations ----------------
// Round-4 change: all three gather kernels get 2-deep software pipelining with dual
// accumulator sets — breaks the serial {index-load -> gather -> fma-chain} dependency
// (one outstanding gather/thread -> two) and halves the fp32 accumulation chain depth.
// fp32-reassociation only; no dtype change (absmax headroom is ~1 ulp, keep it).

// gX = A . X  (50-wide fp32 gather -> fp16 out, rows padded to 64)
__global__ __launch_bounds__(64) void aggX_kernel(const float* __restrict__ X,
                                                  const int* __restrict__ offs,
                                                  const int* __restrict__ csr_src,
                                                  const float* __restrict__ csr_w,
                                                  unsigned short* __restrict__ gX) {
    int n = blockIdx.x;
    int t = threadIdx.x;
    float a0 = 0.0f, a1 = 0.0f;
    if (t < DIN) {
        int p0 = offs[n], p1 = offs[n + 1];
        int p = p0;
        for (; p + 1 < p1; p += 2) {
            int s0 = csr_src[p], s1 = csr_src[p + 1];
            float w0 = csr_w[p], w1 = csr_w[p + 1];
            float x0 = X[(size_t)s0 * DIN + t];
            float x1 = X[(size_t)s1 * DIN + t];
            a0 = fmaf(w0, x0, a0);
            a1 = fmaf(w1, x1, a1);
        }
        if (p < p1) a0 = fmaf(csr_w[p], X[(size_t)csr_src[p] * DIN + t], a0);
    }
    gX[(size_t)n * 64 + t] = (t < DIN) ? f2h(a0 + a1) : (unsigned short)0;
}

// g = A . h, 8 slices x 128 cols, XCD-pinned (measured-best agg variant; further
// slicing refinements were neutral/negative in rounds 10/14/15 — latency/L3-floor)
__global__ __launch_bounds__(256) void agg_slice_kernel(const unsigned short* __restrict__ h,
                                                        const int* __restrict__ offs,
                                                        const int* __restrict__ csr_src,
                                                        const float* __restrict__ csr_w,
                                                        unsigned short* __restrict__ g) {
    const int f = blockIdx.x;
    const int slice = f & 7;
    const int nb = f >> 3;
    const int tid = threadIdx.x;
    const int n = nb * 16 + (tid >> 4);
    const int coloff = slice * 128 + (tid & 15) * 8;
    const unsigned short* hp = h + coloff;

    float a0[8] = {0, 0, 0, 0, 0, 0, 0, 0};
    float a1[8] = {0, 0, 0, 0, 0, 0, 0, 0};
    const int p0 = offs[n], p1 = offs[n + 1];
    int p = p0;
    for (; p + 1 < p1; p += 2) {
        int s0 = csr_src[p], s1 = csr_src[p + 1];
        float w0 = csr_w[p], w1 = csr_w[p + 1];
        uint4 v0 = *(const uint4*)&hp[(size_t)s0 * HID];
        uint4 v1 = *(const uint4*)&hp[(size_t)s1 * HID];
        const unsigned short* q0 = (const unsigned short*)&v0;
        const unsigned short* q1 = (const unsigned short*)&v1;
#pragma unroll
        for (int j = 0; j < 8; ++j) a0[j] = fmaf(w0, h2f(q0[j]), a0[j]);
#pragma unroll
        for (int j = 0; j < 8; ++j) a1[j] = fmaf(w1, h2f(q1[j]), a1[j]);
    }
    if (p < p1) {
        float w0 = csr_w[p];
        uint4 v0 = *(const uint4*)&hp[(size_t)csr_src[p] * HID];
        const unsigned short* q0 = (const unsigned short*)&v0;
#pragma unroll
        for (int j = 0; j < 8; ++j) a0[j] = fmaf(w0, h2f(q0[j]), a0[j]);
    }
    unsigned short ov[8];
#pragma unroll
    for (int j = 0; j < 8; ++j) ov[j] = f2h(a0[j] + a1[j]);
    *(uint4*)&g[(size_t)n * HID + coloff] = *(const uint4*)ov;
}

// layer-3 final, vectorized: 16 lanes/node x 8 cols via uint4 (Q fp16 [N][256]).
// out[n][c] = sum_p w_p * Q[src_p][c] + Q[n][128+c].
__global__ __launch_bounds__(256) void agg3_kernel(const unsigned short* __restrict__ Q,
                                                   const int* __restrict__ offs,
                                                   const int* __restrict__ csr_src,
                                                   const float* __restrict__ csr_w,
                                                   float* __restrict__ out) {
    const int n = blockIdx.x * 16 + (threadIdx.x >> 4);
    const int c0 = (threadIdx.x & 15) * 8;
    float a0[8] = {0, 0, 0, 0, 0, 0, 0, 0};
    float a1[8] = {0, 0, 0, 0, 0, 0, 0, 0};
    const int p0 = offs[n], p1 = offs[n + 1];
    int p = p0;
    for (; p + 1 < p1; p += 2) {
        int s0 = csr_src[p], s1 = csr_src[p + 1];
        float w0 = csr_w[p], w1 = csr_w[p + 1];
        uint4 v0 = *(const uint4*)&Q[(size_t)s0 * NQP + c0];
        uint4 v1 = *(const uint4*)&Q[(size_t)s1 * NQP + c0];
        const unsigned short* q0 = (const unsigned short*)&v0;
        const unsigned short* q1 = (const unsigned short*)&v1;
#pragma unroll
        for (int j = 0; j < 8; ++j) a0[j] = fmaf(w0, h2f(q0[j]), a0[j]);
#pragma unroll
        for (int j = 0; j < 8; ++j) a1[j] = fmaf(w1, h2f(q1[j]), a1[j]);
    }
    if (p < p1) {
        float w0 = csr_w[p];
        uint4 v0 = *(const uint4*)&Q[(size_t)csr_src[p] * NQP + c0];
        const unsigned short* q0 = (const unsigned short*)&v0;
#pragma unroll
        for (int j = 0; j < 8; ++j) a0[j] = fmaf(w0, h2f(q0[j]), a0[j]);
    }
    uint4 sv = *(const uint4*)&Q[(size_t)n * NQP + 128 + c0];
    const unsigned short* ss = (const unsigned short*)&sv;
#pragma unroll
    for (int j = 0; j < 8; ++j) {
        int c = c0 + j;
        if (c < NCLS) out[(size_t)n * NCLS + c] = a0[j] + a1[j] + h2f(ss[j]);
    }
}

// ---------------- fp16 MFMA GEMM: dbuf async pipeline + XOR-swizzled LDS + XCD grouping ----
// Proven 128x128 structure (130 us on layer 2 / MfmaUtil 28% / 0 conflicts). Rounds 1-2
// established the 256x256 low-occupancy schedule cannot beat it on this shape (148/180 us):
// at 2 waves/SIMD the inter-block drift overlap (4 blocks/CU here) is structurally absent.
// EPI 0: elu -> fp16 Co. EPI 1: fp32 atomicAdd (unused here). EPI 2: plain fp16 Co.

#define GBM 128
#define GBN 128
#define GBK 32

template <int EPI>
__global__ __launch_bounds__(256, 4) void mfma_gemm_kernel(
        const unsigned short* __restrict__ Ag, const unsigned short* __restrict__ Ah,
        const unsigned short* __restrict__ Bt,
        void* __restrict__ Co,
        int M, int N, int ldc, int ktot, int khalf, int kw,
        int NB, int MB, int mchunk) {
    __shared__ __align__(16) unsigned short sA[2][GBM * GBK];
    __shared__ __align__(16) unsigned short sB[2][GBN * GBK];

    // --- XCD-grouped block swizzle (round-12 order) ---
    const int f = blockIdx.x;
    const int xcd = f & 7;
    const int r0 = f >> 3;
    const int nB = r0 % NB;
    const int mi = r0 / NB;
    const int mB = xcd * mchunk + mi;
    if (mB >= MB) return;
    const int bm = mB * GBM;
    const int bn = nB * GBN;
    const int ks = blockIdx.y;

    const int tid = threadIdx.x;
    const int lane = tid & 63;
    const int wave = tid >> 6;
    const int wm = wave >> 1;
    const int wn = wave & 1;

    // staging map: thread t covers row (t>>2)+64p; stored chunk slot t&3;
    // global chunk = (t&3) ^ ((row>>1)&3).
    const int st_r = tid >> 2;
    const int st_slot = tid & 3;
    const int st_c = (st_slot ^ ((st_r >> 1) & 3)) * 8;
    const int st_lds = st_r * GBK + st_slot * 8;

    int agm[2], bgn[2];
#pragma unroll
    for (int p = 0; p < 2; ++p) {
        int gm = bm + st_r + p * 64;
        agm[p] = gm < M ? gm : M - 1;
        int gn = bn + st_r + p * 64;
        bgn[p] = gn < N ? gn : N - 1;
    }

    const int frow = lane & 15;
    const int fkc = (((lane >> 4) ^ ((frow >> 1) & 3))) * 8;

    floatx4 acc[4][4];
#pragma unroll
    for (int i = 0; i < 4; ++i)
#pragma unroll
        for (int j = 0; j < 4; ++j) acc[i][j] = (floatx4){0.f, 0.f, 0.f, 0.f};

    auto issue = [&](int k0, int buf) {
        const unsigned short* ap = (k0 < khalf) ? Ag : Ah;
        int ka = (k0 < khalf) ? k0 : k0 - khalf;
#pragma unroll
        for (int p = 0; p < 2; ++p) {
            async16(&ap[(size_t)agm[p] * khalf + ka + st_c],
                    &sA[buf][p * 64 * GBK + st_lds]);
            async16(&Bt[(size_t)bgn[p] * ktot + k0 + st_c],
                    &sB[buf][p * 64 * GBK + st_lds]);
        }
    };

    const int tw = kw / GBK;
    const int t0 = ks * tw;
    const int t1 = t0 + tw;

    issue(t0 * GBK, 0);

    for (int t = t0; t < t1; ++t) {
        __syncthreads();  // drains DMA for tile t (issued one compute-phase ago)
        if (t + 1 < t1) issue((t + 1) * GBK, (t + 1) & 1);

        const unsigned short* a_base = sA[t & 1];
        const unsigned short* b_base = sB[t & 1];
        half8 fa[4], fb[4];
#pragma unroll
        for (int i = 0; i < 4; ++i)
            fa[i] = *(const half8*)&a_base[(wm * 64 + i * 16 + frow) * GBK + fkc];
#pragma unroll
        for (int j = 0; j < 4; ++j)
            fb[j] = *(const half8*)&b_base[(wn * 64 + j * 16 + frow) * GBK + fkc];
#pragma unroll
        for (int i = 0; i < 4; ++i)
#pragma unroll
            for (int j = 0; j < 4; ++j)
                acc[i][j] = __builtin_amdgcn_mfma_f32_16x16x32_f16(fa[i], fb[j], acc[i][j], 0, 0, 0);
    }

    // C/D layout: col=lane&15, row=(lane>>4)*4+reg
    const int c_r0 = (lane >> 4) * 4;
    const int c_c = lane & 15;
#pragma unroll
    for (int i = 0; i < 4; ++i)
#pragma unroll
        for (int j = 0; j < 4; ++j) {
            int gn = bn + wn * 64 + j * 16 + c_c;
            if (gn >= N) continue;
#pragma unroll
            for (int r = 0; r < 4; ++r) {
                int gm = bm + wm * 64 + i * 16 + c_r0 + r;
                if (gm >= M) continue;
                float v = acc[i][j][r];
                if (EPI == 0) {
                    v = v > 0 ? v : expf(v) - 1.0f;  // elu
                    ((unsigned short*)Co)[(size_t)gm * ldc + gn] = f2h(v);
                } else if (EPI == 1) {
                    atomicAdd(&((float*)Co)[(size_t)gm * ldc + gn], v);
                } else {
                    ((unsigned short*)Co)[(size_t)gm * ldc + gn] = f2h(v);
                }
            }
        }
}

// ---------------- launch ----------------

static inline size_t align_up(size_t x, size_t a) { return (x + a - 1) & ~(a - 1); }

extern "C" void kernel_launch(void* const* d_in, const int* in_sizes, int n_in,
                              void* d_out, int out_size, void* d_ws, size_t ws_size,
                              hipStream_t stream) {
    const float* X  = (const float*)d_in[0];
    const int* erow = (const int*)d_in[1];
    const int* ecol = (const int*)d_in[1] + N_EDGES;
    const float* W1 = (const float*)d_in[2];
    const float* W2 = (const float*)d_in[3];
    const float* S2 = (const float*)d_in[4];
    const float* W3 = (const float*)d_in[5];
    const float* S3 = (const float*)d_in[6];
    float* out = (float*)d_out;

    // workspace carve-up
    char* w = (char*)d_ws;
    int* deg     = (int*)w;             w += align_up((size_t)N_NODES * 4, 256);
    int* offs    = (int*)w;             w += align_up((size_t)(N_NODES + 1) * 4, 256);
    int* cursor  = (int*)w;             w += align_up((size_t)N_NODES * 4, 256);
    int* csr_src = (int*)w;             w += align_up((size_t)N_EDGES * 4, 256);
    float* dis   = (float*)w;           w += align_up((size_t)N_NODES * 4, 256);
    float* csr_w = (float*)w;           w += align_up((size_t)N_EDGES * 4, 256);
    unsigned short* gXh = (unsigned short*)w; w += align_up((size_t)N_NODES * 64 * 2, 256);
    unsigned short* h1 = (unsigned short*)w;  w += align_up((size_t)N_NODES * HID * 2, 256);
    unsigned short* g  = (unsigned short*)w;  w += align_up((size_t)N_NODES * HID * 2, 256);
    unsigned short* h2 = (unsigned short*)w;  w += align_up((size_t)N_NODES * HID * 2, 256);
    unsigned short* Qh = (unsigned short*)w;  w += align_up((size_t)N_NODES * NQP * 2, 256);
    unsigned short* Bt1 = (unsigned short*)w; w += align_up((size_t)HID * 64 * 2, 256);
    unsigned short* Bt2 = (unsigned short*)w; w += align_up((size_t)HID * KCAT * 2, 256);
    unsigned short* Bt3 = (unsigned short*)w; w += align_up((size_t)256 * HID * 2, 256);

    const int TB = 256;
    int nb_n = (N_NODES + TB - 1) / TB;

    // 1. zero deg; 2. merged prep (count_deg + all weight prep)
    zero_int_kernel<<<nb_n, TB, 0, stream>>>(deg, N_NODES);
    prep_kernel<<<3810, 256, 0, stream>>>(ecol, deg, W1, Bt1, W2, S2, Bt2, W3, S3, Bt3);

    // 3. scan; 4. scatter
    scan_kernel<<<1, 1024, 0, stream>>>(deg, offs, cursor, dis, N_NODES, N_EDGES);
    scatter_kernel<<<(N_EDGES + TB - 1) / TB, TB, 0, stream>>>(erow, ecol, dis, cursor,
                                                               csr_src, csr_w, N_EDGES);

    const int MB = (N_NODES + GBM - 1) / GBM;   // 157
    const int mchunk = (MB + 7) / 8;            // 20
    const int NB2 = HID / GBN;                  // 8
    const int NB3 = NQP / GBN;                  // 2 (exact, no masking holes)
    const int AGG_GRID = 8 * (N_NODES / 16);    // 8 slices x 1250 node-blocks

    // 5-6. layer 1: gX = A.X ; h1 = elu(gX @ W1)
    aggX_kernel<<<N_NODES, 64, 0, stream>>>(X, offs, csr_src, csr_w, gXh);
    mfma_gemm_kernel<0><<<dim3(8 * mchunk * NB2, 1), 256, 0, stream>>>(
        gXh, gXh, Bt1, h1, N_NODES, HID, HID, 64, 64, 64, NB2, MB, mchunk);

    // 7-8. layer 2: g1 = A.h1 ; h2 = elu([g1|h1] @ [W2;S2])
    agg_slice_kernel<<<AGG_GRID, 256, 0, stream>>>(h1, offs, csr_src, csr_w, g);
    mfma_gemm_kernel<0><<<dim3(8 * mchunk * NB2, 1), 256, 0, stream>>>(
        g, h1, Bt2, h2, N_NODES, HID, HID, KCAT, HID, KCAT, NB2, MB, mchunk);

    // 9-10. layer 3 (project-then-aggregate): Q = h2 @ [W3bar|S3bar] (fp16, padded 256);
    //        out = agg(Q_w) + Q_s
    mfma_gemm_kernel<2><<<dim3(8 * mchunk * NB3, 1), 256, 0, stream>>>(
        h2, h2, Bt3, Qh, N_NODES, NQP, NQP, HID, HID, HID, NB3, MB, mchunk);
    agg3_kernel<<<N_NODES / 16, 256, 0, stream>>>(Qh, offs, csr_src, csr_w, out);
}

// Round 5
// 410.955 us; speedup vs baseline: 1.3054x; 1.0063x over previous
//
#include <hip/hip_runtime.h>
#include <hip/hip_bf16.h>
#include <math.h>

#define N_NODES 20000
#define N_EDGES 320000
#define DIN 50
#define HID 1024
#define NC3 726   // 6*121
#define NCLS 121
#define KCAT 2048
#define NQP 256   // padded [W3bar(128) | S3bar(128)] projected width (16B-aligned rows)

typedef __attribute__((ext_vector_type(8))) _Float16 half8;
typedef __attribute__((ext_vector_type(4))) float floatx4;

__device__ __forceinline__ unsigned short f2h(float v) {
    _Float16 h = (_Float16)v;
    return __builtin_bit_cast(unsigned short, h);
}
__device__ __forceinline__ float h2f(unsigned short u) {
    return (float)__builtin_bit_cast(_Float16, u);
}

// async global->LDS, 16B per lane. LDS dest must equal wave-uniform base + lane*16.
__device__ __forceinline__ void async16(const void* g, void* l) {
    __builtin_amdgcn_global_load_lds(
        (const __attribute__((address_space(1))) void*)g,
        (__attribute__((address_space(3))) void*)l,
        16, 0, 0);
}

// ---------------- CSR build ----------------

__global__ void zero_int_kernel(int* p, int n) {
    int i = blockIdx.x * blockDim.x + threadIdx.x;
    if (i < n) p[i] = 0;
}

// exclusive scan of deg -> offs/cursor; also emits dis = deg^-1/2
__global__ __launch_bounds__(1024) void scan_kernel(const int* __restrict__ deg,
                                                    int* __restrict__ offs,
                                                    int* __restrict__ cursor,
                                                    float* __restrict__ dis,
                                                    int n, int total) {
    __shared__ int part[1024];
    int t = threadIdx.x;
    const int CH = (n + 1023) / 1024;
    int base0 = t * CH;
    int s = 0;
    for (int i = 0; i < CH; ++i) {
        int idx = base0 + i;
        if (idx < n) s += deg[idx];
    }
    part[t] = s;
    __syncthreads();
    for (int d = 1; d < 1024; d <<= 1) {
        int v = (t >= d) ? part[t - d] : 0;
        __syncthreads();
        part[t] += v;
        __syncthreads();
    }
    int run = part[t] - s;
    for (int i = 0; i < CH; ++i) {
        int idx = base0 + i;
        if (idx < n) {
            int d = deg[idx];
            offs[idx] = run;
            cursor[idx] = run;
            dis[idx] = d > 0 ? rsqrtf((float)d) : 0.0f;
            run += d;
        }
    }
    if (t == 1023) offs[n] = total;
}

// scatter with inline norm = dis[row]*dis[col]
__global__ void scatter_kernel(const int* __restrict__ row, const int* __restrict__ col,
                               const float* __restrict__ dis, int* __restrict__ cursor,
                               int* __restrict__ csr_src, float* __restrict__ csr_w, int e) {
    int i = blockIdx.x * blockDim.x + threadIdx.x;
    if (i < e) {
        int r = row[i], c = col[i];
        float nm = dis[r] * dis[c];
        int pos = atomicAdd(&cursor[c], 1);
        csr_src[pos] = r;
        csr_w[pos] = nm;
    }
}

// ---------------- merged prep: count_deg + w1t + wt2 transpose + wt3 fold+transpose ----
// blockIdx ranges:  [0,2048) wt2 | [2048,2304) wt3 | [2304,2560) w1t | [2560,3810) count_deg
__global__ __launch_bounds__(256) void prep_kernel(const int* __restrict__ ecol,
                                                   int* __restrict__ deg,
                                                   const float* __restrict__ W1,
                                                   unsigned short* __restrict__ Bt1,
                                                   const float* __restrict__ W2,
                                                   const float* __restrict__ S2,
                                                   unsigned short* __restrict__ Bt2,
                                                   const float* __restrict__ W3,
                                                   const float* __restrict__ S3,
                                                   unsigned short* __restrict__ Bt3) {
    __shared__ unsigned short tile[32][33];
    const int b = blockIdx.x;
    const int tid = threadIdx.x;

    if (b < 2048) {
        // W2/S2 [1024][1024] -> Bt2 fp16 [1024][2048] transposed via LDS 32x32 tiles
        int src = b >> 10;
        int t = b & 1023;
        int k0 = (t >> 5) * 32;
        int n0 = (t & 31) * 32;
        const float* W = src ? S2 : W2;
        int koff = src ? HID : 0;
        int tx = tid & 31;
        int ty = tid >> 5;
#pragma unroll
        for (int r = 0; r < 32; r += 8)
            tile[ty + r][tx] = f2h(W[(size_t)(k0 + ty + r) * HID + n0 + tx]);
        __syncthreads();
#pragma unroll
        for (int r = 0; r < 32; r += 8)
            Bt2[(size_t)(n0 + ty + r) * KCAT + koff + k0 + tx] = tile[tx][ty + r];
    } else if (b < 2304) {
        // W3/S3 [1024][726] -> head-mean + transpose -> Bt3 fp16 [2*128][1024] (pad rows 0)
        int tb = b - 2048;
        int src = tb >> 7;
        int t = tb & 127;
        int k0 = (t >> 2) * 32;
        int c0 = (t & 3) * 32;
        const float* W = src ? S3 : W3;
        int tx = tid & 31;
        int ty = tid >> 5;
#pragma unroll
        for (int r = 0; r < 32; r += 8) {
            int k = k0 + ty + r, c = c0 + tx;
            float v = 0.0f;
            if (c < NCLS) {
                const float* p = W + (size_t)k * NC3 + c;
                v = (p[0] + p[121] + p[242] + p[363] + p[484] + p[605]) * (1.0f / 6.0f);
            }
            tile[ty + r][tx] = f2h(v);
        }
        __syncthreads();
#pragma unroll
        for (int r = 0; r < 32; r += 8) {
            int c = c0 + ty + r;   // always < 128; pad cols carry 0 so Qh pads are defined
            Bt3[(size_t)(src * 128 + c) * HID + k0 + tx] = tile[tx][ty + r];
        }
    } else if (b < 2560) {
        // W1 [50][1024] -> Bt1 fp16 [1024][64] transposed, padded
        int i = (b - 2304) * 256 + tid;
        int n = i / 64, k = i - n * 64;
        Bt1[i] = (k < DIN) ? f2h(W1[(size_t)k * HID + n]) : (unsigned short)0;
    } else {
        // degree count
        int i = (b - 2560) * 256 + tid;
        if (i < N_EDGES) atomicAdd(&deg[ecol[i]], 1);
    }
}

// ---------------- aggregations ----------------
// All three gather kernels: 2-deep software pipeline + dual accumulator sets (round 4,
// measured -38 us total). fp32-reassociation only.

// gX = A . X  (50-wide fp32 gather -> fp16 out, rows padded to 64)
__global__ __launch_bounds__(64) void aggX_kernel(const float* __restrict__ X,
                                                  const int* __restrict__ offs,
                                                  const int* __restrict__ csr_src,
                                                  const float* __restrict__ csr_w,
                                                  unsigned short* __restrict__ gX) {
    int n = blockIdx.x;
    int t = threadIdx.x;
    float a0 = 0.0f, a1 = 0.0f;
    if (t < DIN) {
        int p0 = offs[n], p1 = offs[n + 1];
        int p = p0;
        for (; p + 1 < p1; p += 2) {
            int s0 = csr_src[p], s1 = csr_src[p + 1];
            float w0 = csr_w[p], w1 = csr_w[p + 1];
            float x0 = X[(size_t)s0 * DIN + t];
            float x1 = X[(size_t)s1 * DIN + t];
            a0 = fmaf(w0, x0, a0);
            a1 = fmaf(w1, x1, a1);
        }
        if (p < p1) a0 = fmaf(csr_w[p], X[(size_t)csr_src[p] * DIN + t], a0);
    }
    gX[(size_t)n * 64 + t] = (t < DIN) ? f2h(a0 + a1) : (unsigned short)0;
}

// g = A . h, 8 slices x 128 cols, XCD-pinned (measured-best agg variant)
__global__ __launch_bounds__(256) void agg_slice_kernel(const unsigned short* __restrict__ h,
                                                        const int* __restrict__ offs,
                                                        const int* __restrict__ csr_src,
                                                        const float* __restrict__ csr_w,
                                                        unsigned short* __restrict__ g) {
    const int f = blockIdx.x;
    const int slice = f & 7;
    const int nb = f >> 3;
    const int tid = threadIdx.x;
    const int n = nb * 16 + (tid >> 4);
    const int coloff = slice * 128 + (tid & 15) * 8;
    const unsigned short* hp = h + coloff;

    float a0[8] = {0, 0, 0, 0, 0, 0, 0, 0};
    float a1[8] = {0, 0, 0, 0, 0, 0, 0, 0};
    const int p0 = offs[n], p1 = offs[n + 1];
    int p = p0;
    for (; p + 1 < p1; p += 2) {
        int s0 = csr_src[p], s1 = csr_src[p + 1];
        float w0 = csr_w[p], w1 = csr_w[p + 1];
        uint4 v0 = *(const uint4*)&hp[(size_t)s0 * HID];
        uint4 v1 = *(const uint4*)&hp[(size_t)s1 * HID];
        const unsigned short* q0 = (const unsigned short*)&v0;
        const unsigned short* q1 = (const unsigned short*)&v1;
#pragma unroll
        for (int j = 0; j < 8; ++j) a0[j] = fmaf(w0, h2f(q0[j]), a0[j]);
#pragma unroll
        for (int j = 0; j < 8; ++j) a1[j] = fmaf(w1, h2f(q1[j]), a1[j]);
    }
    if (p < p1) {
        float w0 = csr_w[p];
        uint4 v0 = *(const uint4*)&hp[(size_t)csr_src[p] * HID];
        const unsigned short* q0 = (const unsigned short*)&v0;
#pragma unroll
        for (int j = 0; j < 8; ++j) a0[j] = fmaf(w0, h2f(q0[j]), a0[j]);
    }
    unsigned short ov[8];
#pragma unroll
    for (int j = 0; j < 8; ++j) ov[j] = f2h(a0[j] + a1[j]);
    *(uint4*)&g[(size_t)n * HID + coloff] = *(const uint4*)ov;
}

// layer-3 final, vectorized: 16 lanes/node x 8 cols via uint4 (Q fp16 [N][256]).
// out[n][c] = sum_p w_p * Q[src_p][c] + Q[n][128+c].
__global__ __launch_bounds__(256) void agg3_kernel(const unsigned short* __restrict__ Q,
                                                   const int* __restrict__ offs,
                                                   const int* __restrict__ csr_src,
                                                   const float* __restrict__ csr_w,
                                                   float* __restrict__ out) {
    const int n = blockIdx.x * 16 + (threadIdx.x >> 4);
    const int c0 = (threadIdx.x & 15) * 8;
    float a0[8] = {0, 0, 0, 0, 0, 0, 0, 0};
    float a1[8] = {0, 0, 0, 0, 0, 0, 0, 0};
    const int p0 = offs[n], p1 = offs[n + 1];
    int p = p0;
    for (; p + 1 < p1; p += 2) {
        int s0 = csr_src[p], s1 = csr_src[p + 1];
        float w0 = csr_w[p], w1 = csr_w[p + 1];
        uint4 v0 = *(const uint4*)&Q[(size_t)s0 * NQP + c0];
        uint4 v1 = *(const uint4*)&Q[(size_t)s1 * NQP + c0];
        const unsigned short* q0 = (const unsigned short*)&v0;
        const unsigned short* q1 = (const unsigned short*)&v1;
#pragma unroll
        for (int j = 0; j < 8; ++j) a0[j] = fmaf(w0, h2f(q0[j]), a0[j]);
#pragma unroll
        for (int j = 0; j < 8; ++j) a1[j] = fmaf(w1, h2f(q1[j]), a1[j]);
    }
    if (p < p1) {
        float w0 = csr_w[p];
        uint4 v0 = *(const uint4*)&Q[(size_t)csr_src[p] * NQP + c0];
        const unsigned short* q0 = (const unsigned short*)&v0;
#pragma unroll
        for (int j = 0; j < 8; ++j) a0[j] = fmaf(w0, h2f(q0[j]), a0[j]);
    }
    uint4 sv = *(const uint4*)&Q[(size_t)n * NQP + 128 + c0];
    const unsigned short* ss = (const unsigned short*)&sv;
#pragma unroll
    for (int j = 0; j < 8; ++j) {
        int c = c0 + j;
        if (c < NCLS) out[(size_t)n * NCLS + c] = a0[j] + a1[j] + h2f(ss[j]);
    }
}

// ---------------- fp16 MFMA GEMM: depth-2 async pipeline + XOR-swizzled LDS + XCD grouping
// Round-5 change: PIPE-buffer LDS ring (PIPE=3 -> prefetch depth 2) with counted
// vmcnt(4) waits instead of __syncthreads' full drain. Theory: A streams from HBM
// (~900 cy miss); depth-1 prefetch gives only a ~1-k-step shadow (~300-600 cy) ->
// ~47% no-issue cycles at depth 1. Depth 2 doubles the shadow. Cost: 48 KB LDS ->
// 3 blocks/CU (was 5). Precommit: if gemm2 >= 128 us, revert to PIPE=2.
// Ring hazard check: issue(t+2) overwrites buf[(t+2)%3] = buf[(t-1)%3], whose
// ds_reads completed before the top-of-t barrier (compiler lgkmcnt waits precede
// the pre-barrier MFMAs). One barrier + one counted vmcnt per K-step.
// EPI 0: elu -> fp16 Co. EPI 1: fp32 atomicAdd (unused). EPI 2: plain fp16 Co.

#define GBM 128
#define GBN 128
#define GBK 32
#define PIPE 3

template <int EPI>
__global__ __launch_bounds__(256, 4) void mfma_gemm_kernel(
        const unsigned short* __restrict__ Ag, const unsigned short* __restrict__ Ah,
        const unsigned short* __restrict__ Bt,
        void* __restrict__ Co,
        int M, int N, int ldc, int ktot, int khalf, int kw,
        int NB, int MB, int mchunk) {
    __shared__ __align__(16) unsigned short sA[PIPE][GBM * GBK];
    __shared__ __align__(16) unsigned short sB[PIPE][GBN * GBK];

    // --- XCD-grouped block swizzle (round-12 order) ---
    const int f = blockIdx.x;
    const int xcd = f & 7;
    const int r0 = f >> 3;
    const int nB = r0 % NB;
    const int mi = r0 / NB;
    const int mB = xcd * mchunk + mi;
    if (mB >= MB) return;
    const int bm = mB * GBM;
    const int bn = nB * GBN;
    const int ks = blockIdx.y;

    const int tid = threadIdx.x;
    const int lane = tid & 63;
    const int wave = tid >> 6;
    const int wm = wave >> 1;
    const int wn = wave & 1;

    // staging map: thread t covers row (t>>2)+64p; stored chunk slot t&3;
    // global chunk = (t&3) ^ ((row>>1)&3).
    const int st_r = tid >> 2;
    const int st_slot = tid & 3;
    const int st_c = (st_slot ^ ((st_r >> 1) & 3)) * 8;
    const int st_lds = st_r * GBK + st_slot * 8;

    int agm[2], bgn[2];
#pragma unroll
    for (int p = 0; p < 2; ++p) {
        int gm = bm + st_r + p * 64;
        agm[p] = gm < M ? gm : M - 1;
        int gn = bn + st_r + p * 64;
        bgn[p] = gn < N ? gn : N - 1;
    }

    const int frow = lane & 15;
    const int fkc = (((lane >> 4) ^ ((frow >> 1) & 3))) * 8;

    floatx4 acc[4][4];
#pragma unroll
    for (int i = 0; i < 4; ++i)
#pragma unroll
        for (int j = 0; j < 4; ++j) acc[i][j] = (floatx4){0.f, 0.f, 0.f, 0.f};

    auto issue = [&](int k0, int buf) {
        const unsigned short* ap = (k0 < khalf) ? Ag : Ah;
        int ka = (k0 < khalf) ? k0 : k0 - khalf;
#pragma unroll
        for (int p = 0; p < 2; ++p) {
            async16(&ap[(size_t)agm[p] * khalf + ka + st_c],
                    &sA[buf][p * 64 * GBK + st_lds]);
            async16(&Bt[(size_t)bgn[p] * ktot + k0 + st_c],
                    &sB[buf][p * 64 * GBK + st_lds]);
        }
    };

    const int tw = kw / GBK;
    const int t0 = ks * tw;
    const int t1 = t0 + tw;

    // prologue: depth-2 prefetch (tiles t0, t0+1) -> 8 loads in flight per wave
    issue(t0 * GBK, 0);
    if (t0 + 1 < t1) issue((t0 + 1) * GBK, 1);

    for (int t = t0; t < t1; ++t) {
        // counted wait: tile t's 4 loads landed; tile t+1's may stay in flight
        if (t + 1 < t1) { asm volatile("s_waitcnt vmcnt(4)" ::: "memory"); }
        else            { asm volatile("s_waitcnt vmcnt(0)" ::: "memory"); }
        __builtin_amdgcn_s_barrier();
        if (t + 2 < t1) issue((t + 2) * GBK, (t + 2 - t0) % PIPE);

        const unsigned short* a_base = sA[(t - t0) % PIPE];
        const unsigned short* b_base = sB[(t - t0) % PIPE];
        half8 fa[4], fb[4];
#pragma unroll
        for (int i = 0; i < 4; ++i)
            fa[i] = *(const half8*)&a_base[(wm * 64 + i * 16 + frow) * GBK + fkc];
#pragma unroll
        for (int j = 0; j < 4; ++j)
            fb[j] = *(const half8*)&b_base[(wn * 64 + j * 16 + frow) * GBK + fkc];
#pragma unroll
        for (int i = 0; i < 4; ++i)
#pragma unroll
            for (int j = 0; j < 4; ++j)
                acc[i][j] = __builtin_amdgcn_mfma_f32_16x16x32_f16(fa[i], fb[j], acc[i][j], 0, 0, 0);
    }

    // C/D layout: col=lane&15, row=(lane>>4)*4+reg
    const int c_r0 = (lane >> 4) * 4;
    const int c_c = lane & 15;
#pragma unroll
    for (int i = 0; i < 4; ++i)
#pragma unroll
        for (int j = 0; j < 4; ++j) {
            int gn = bn + wn * 64 + j * 16 + c_c;
            if (gn >= N) continue;
#pragma unroll
            for (int r = 0; r < 4; ++r) {
                int gm = bm + wm * 64 + i * 16 + c_r0 + r;
                if (gm >= M) continue;
                float v = acc[i][j][r];
                if (EPI == 0) {
                    v = v > 0 ? v : expf(v) - 1.0f;  // elu
                    ((unsigned short*)Co)[(size_t)gm * ldc + gn] = f2h(v);
                } else if (EPI == 1) {
                    atomicAdd(&((float*)Co)[(size_t)gm * ldc + gn], v);
                } else {
                    ((unsigned short*)Co)[(size_t)gm * ldc + gn] = f2h(v);
                }
            }
        }
}

// ---------------- launch ----------------

static inline size_t align_up(size_t x, size_t a) { return (x + a - 1) & ~(a - 1); }

extern "C" void kernel_launch(void* const* d_in, const int* in_sizes, int n_in,
                              void* d_out, int out_size, void* d_ws, size_t ws_size,
                              hipStream_t stream) {
    const float* X  = (const float*)d_in[0];
    const int* erow = (const int*)d_in[1];
    const int* ecol = (const int*)d_in[1] + N_EDGES;
    const float* W1 = (const float*)d_in[2];
    const float* W2 = (const float*)d_in[3];
    const float* S2 = (const float*)d_in[4];
    const float* W3 = (const float*)d_in[5];
    const float* S3 = (const float*)d_in[6];
    float* out = (float*)d_out;

    // workspace carve-up
    char* w = (char*)d_ws;
    int* deg     = (int*)w;             w += align_up((size_t)N_NODES * 4, 256);
    int* offs    = (int*)w;             w += align_up((size_t)(N_NODES + 1) * 4, 256);
    int* cursor  = (int*)w;             w += align_up((size_t)N_NODES * 4, 256);
    int* csr_src = (int*)w;             w += align_up((size_t)N_EDGES * 4, 256);
    float* dis   = (float*)w;           w += align_up((size_t)N_NODES * 4, 256);
    float* csr_w = (float*)w;           w += align_up((size_t)N_EDGES * 4, 256);
    unsigned short* gXh = (unsigned short*)w; w += align_up((size_t)N_NODES * 64 * 2, 256);
    unsigned short* h1 = (unsigned short*)w;  w += align_up((size_t)N_NODES * HID * 2, 256);
    unsigned short* g  = (unsigned short*)w;  w += align_up((size_t)N_NODES * HID * 2, 256);
    unsigned short* h2 = (unsigned short*)w;  w += align_up((size_t)N_NODES * HID * 2, 256);
    unsigned short* Qh = (unsigned short*)w;  w += align_up((size_t)N_NODES * NQP * 2, 256);
    unsigned short* Bt1 = (unsigned short*)w; w += align_up((size_t)HID * 64 * 2, 256);
    unsigned short* Bt2 = (unsigned short*)w; w += align_up((size_t)HID * KCAT * 2, 256);
    unsigned short* Bt3 = (unsigned short*)w; w += align_up((size_t)256 * HID * 2, 256);

    const int TB = 256;
    int nb_n = (N_NODES + TB - 1) / TB;

    // 1. zero deg; 2. merged prep (count_deg + all weight prep)
    zero_int_kernel<<<nb_n, TB, 0, stream>>>(deg, N_NODES);
    prep_kernel<<<3810, 256, 0, stream>>>(ecol, deg, W1, Bt1, W2, S2, Bt2, W3, S3, Bt3);

    // 3. scan; 4. scatter
    scan_kernel<<<1, 1024, 0, stream>>>(deg, offs, cursor, dis, N_NODES, N_EDGES);
    scatter_kernel<<<(N_EDGES + TB - 1) / TB, TB, 0, stream>>>(erow, ecol, dis, cursor,
                                                               csr_src, csr_w, N_EDGES);

    const int MB = (N_NODES + GBM - 1) / GBM;   // 157
    const int mchunk = (MB + 7) / 8;            // 20
    const int NB2 = HID / GBN;                  // 8
    const int NB3 = NQP / GBN;                  // 2 (exact, no masking holes)
    const int AGG_GRID = 8 * (N_NODES / 16);    // 8 slices x 1250 node-blocks

    // 5-6. layer 1: gX = A.X ; h1 = elu(gX @ W1)
    aggX_kernel<<<N_NODES, 64, 0, stream>>>(X, offs, csr_src, csr_w, gXh);
    mfma_gemm_kernel<0><<<dim3(8 * mchunk * NB2, 1), 256, 0, stream>>>(
        gXh, gXh, Bt1, h1, N_NODES, HID, HID, 64, 64, 64, NB2, MB, mchunk);

    // 7-8. layer 2: g1 = A.h1 ; h2 = elu([g1|h1] @ [W2;S2])
    agg_slice_kernel<<<AGG_GRID, 256, 0, stream>>>(h1, offs, csr_src, csr_w, g);
    mfma_gemm_kernel<0><<<dim3(8 * mchunk * NB2, 1), 256, 0, stream>>>(
        g, h1, Bt2, h2, N_NODES, HID, HID, KCAT, HID, KCAT, NB2, MB, mchunk);

    // 9-10. layer 3 (project-then-aggregate): Q = h2 @ [W3bar|S3bar] (fp16, padded 256);
    //        out = agg(Q_w) + Q_s
    mfma_gemm_kernel<2><<<dim3(8 * mchunk * NB3, 1), 256, 0, stream>>>(
        h2, h2, Bt3, Qh, N_NODES, NQP, NQP, HID, HID, HID, NB3, MB, mchunk);
    agg3_kernel<<<N_NODES / 16, 256, 0, stream>>>(Qh, offs, csr_src, csr_w, out);
}